// Round 7
// baseline (1519.467 us; speedup 1.0000x reference)
//
#include <hip/hip_runtime.h>
#include <math.h>

#define Bdim 8
#define Ldim 1024
#define Pdim 64
#define Hdim 512
#define NLdim 4
#define DIN 1024
#define NST 16
#define DTR 32
#define Mrows (Bdim * Ldim)   // 8192
#define CHUNK 64
#define NCHUNK (Ldim / CHUNK) // 16

typedef unsigned int u32;
typedef __attribute__((ext_vector_type(8))) short bf16x8;
typedef __attribute__((ext_vector_type(4))) float f32x4;

__device__ __forceinline__ short f2bf(float f) {
  union { float f; u32 u; } v; v.f = f;
  u32 r = v.u + 0x7fffu + ((v.u >> 16) & 1u);
  return (short)(r >> 16);
}
__device__ __forceinline__ float bf2f(short h) {
  union { u32 u; float f; } v; v.u = ((u32)(unsigned short)h) << 16;
  return v.f;
}
// fp32 -> packed [hi|lo] bf16 pair (hi = element 2k in memory)
__device__ __forceinline__ u32 packpair(float x) {
  short hi = f2bf(x);
  short lo = f2bf(x - bf2f(hi));
  return (u32)(unsigned short)hi | ((u32)(unsigned short)lo << 16);
}
__device__ __forceinline__ bf16x8 pairswap(bf16x8 v) {
  union { bf16x8 v; u32 u[4]; } a, b;
  a.v = v;
  #pragma unroll
  for (int i = 0; i < 4; ++i) b.u[i] = (a.u[i] << 16) | (a.u[i] >> 16);
  return b.v;
}
__device__ __forceinline__ void gld16(const short* g, short* l) {
  __builtin_amdgcn_global_load_lds(
      (const __attribute__((address_space(1))) void*)g,
      (__attribute__((address_space(3))) void*)l, 16, 0, 0);
}
__device__ __forceinline__ int swz(int r) { return (r & 3) ^ ((r >> 2) & 3); }

// ---------------------------------------------------------------------------
// minmax-normalize + LayerNorm, one wave per row of 64 elements
// ---------------------------------------------------------------------------
__global__ __launch_bounds__(256) void ln_kernel(
    const float* __restrict__ x, const float* __restrict__ g,
    const float* __restrict__ bta, float* __restrict__ xl) {
  int row = blockIdx.x * 4 + (threadIdx.x >> 6);
  int lane = threadIdx.x & 63;
  float v = x[(size_t)row * Pdim + lane];
  float mn = v, mx = v;
  #pragma unroll
  for (int m = 1; m < 64; m <<= 1) {
    mn = fminf(mn, __shfl_xor(mn, m, 64));
    mx = fmaxf(mx, __shfl_xor(mx, m, 64));
  }
  float xn = (v - mn) / (mx - mn + 1e-6f);
  float s = xn, s2 = xn * xn;
  #pragma unroll
  for (int m = 1; m < 64; m <<= 1) {
    s += __shfl_xor(s, m, 64);
    s2 += __shfl_xor(s2, m, 64);
  }
  float mu = s * (1.f / 64.f);
  float var = s2 * (1.f / 64.f) - mu * mu;
  float out = (xn - mu) * rsqrtf(var + 1e-5f) * g[lane] + bta[lane];
  xl[(size_t)row * Pdim + lane] = out;
}

// ---------------------------------------------------------------------------
// elementwise fp32 -> packed bf16-pair. single buffer version
// ---------------------------------------------------------------------------
__global__ __launch_bounds__(256) void pair_split_kernel(
    const float* __restrict__ X, u32* __restrict__ Xp) {
  int i = (blockIdx.x * 256 + threadIdx.x) * 4;
  float4 v = *(const float4*)&X[i];
  uint4 o;
  o.x = packpair(v.x); o.y = packpair(v.y);
  o.z = packpair(v.z); o.w = packpair(v.w);
  *(uint4*)&Xp[i] = o;
}

// two-buffer version (h + w_in in one dispatch)
__global__ __launch_bounds__(256) void pair_split2_kernel(
    const float* __restrict__ X0, u32* __restrict__ P0, int nblk0,
    const float* __restrict__ X1, u32* __restrict__ P1) {
  int blk = blockIdx.x;
  const float* X;
  u32* P;
  int i;
  if (blk < nblk0) {
    X = X0; P = P0; i = (blk * 256 + threadIdx.x) * 4;
  } else {
    X = X1; P = P1; i = ((blk - nblk0) * 256 + threadIdx.x) * 4;
  }
  float4 v = *(const float4*)&X[i];
  uint4 o;
  o.x = packpair(v.x); o.y = packpair(v.y);
  o.z = packpair(v.z); o.w = packpair(v.w);
  *(uint4*)&P[i] = o;
}

// ---------------------------------------------------------------------------
// bf16-pair MFMA GEMM: C(M,Nx) = A(M,K as pairs) * W(Nx,K)^T, fp32 out.
// XOR-swizzled LDS (conflict-free frag reads), BK=64 shorts (2 subtiles per
// barrier pair). Tile 128 x TN (128 or 64), 256 threads.
// ---------------------------------------------------------------------------
template <int TN>
__global__ __launch_bounds__(256) void gemm_pair(
    const short* __restrict__ Ab, const short* __restrict__ Wb,
    float* __restrict__ C, int Kp, int ldc) {
  constexpr int FM = (TN == 128) ? 4 : 2;
  constexpr int FN = 4;
  constexpr int BUNITS = TN * 4;            // units per B subtile
  __shared__ short As[2 * 128 * 32];        // 2 subtiles of 512 units
  __shared__ short Bs[2 * TN * 32];
  int tid = threadIdx.x;
  int lane = tid & 63;
  int wave = tid >> 6;
  int quad = lane >> 4, l16 = lane & 15;
  int wm = (TN == 128) ? (wave & 1) * 64 : wave * 32;
  int wn = (TN == 128) ? (wave >> 1) * 64 : 0;
  int row0 = blockIdx.y * 128, col0 = blockIdx.x * TN;

  f32x4 acc[FM][FN];
  #pragma unroll
  for (int i = 0; i < FM; ++i)
    #pragma unroll
    for (int j = 0; j < FN; ++j) acc[i][j] = (f32x4){0.f, 0.f, 0.f, 0.f};

  // staging: unit u holds global (row=u>>2, k8=((u&3)^swz(row)) + 4*subtile)
  int uA0 = tid, uA1 = tid + 256;
  const short* gA0 =
      Ab + (size_t)(row0 + (uA0 >> 2)) * Kp + (((uA0 & 3) ^ swz(uA0 >> 2)) << 3);
  const short* gA1 =
      Ab + (size_t)(row0 + (uA1 >> 2)) * Kp + (((uA1 & 3) ^ swz(uA1 >> 2)) << 3);
  short* lA0 = &As[uA0 * 8];
  short* lA1 = &As[uA1 * 8];
  const short* gB0 =
      Wb + (size_t)(col0 + (uA0 >> 2)) * Kp + (((uA0 & 3) ^ swz(uA0 >> 2)) << 3);
  short* lB0 = &Bs[uA0 * 8];
  const short* gB1 = nullptr;
  short* lB1 = nullptr;
  if (TN == 128) {
    gB1 = Wb + (size_t)(col0 + (uA1 >> 2)) * Kp +
          (((uA1 & 3) ^ swz(uA1 >> 2)) << 3);
    lB1 = &Bs[uA1 * 8];
  }

  // frag LDS offsets (shorts), subtile 0
  int aoff[FM], boff[FN];
  #pragma unroll
  for (int t = 0; t < FM; ++t) {
    int r = wm + t * 16 + l16;
    aoff[t] = (r * 4 + (quad ^ swz(r))) * 8;
  }
  #pragma unroll
  for (int t = 0; t < FN; ++t) {
    int r = wn + t * 16 + l16;
    boff[t] = (r * 4 + (quad ^ swz(r))) * 8;
  }

  for (int k0 = 0; k0 < Kp; k0 += 64) {
    __syncthreads();
    // subtile 0 at k0, subtile 1 at k0+32
    gld16(gA0 + k0, lA0);
    gld16(gA0 + k0 + 32, lA0 + 4096);
    gld16(gA1 + k0, lA1);
    gld16(gA1 + k0 + 32, lA1 + 4096);
    gld16(gB0 + k0, lB0);
    gld16(gB0 + k0 + 32, lB0 + BUNITS * 8);
    if (TN == 128) {
      gld16(gB1 + k0, lB1);
      gld16(gB1 + k0 + 32, lB1 + BUNITS * 8);
    }
    __syncthreads();
    #pragma unroll
    for (int s = 0; s < 2; ++s) {
      bf16x8 af[FM], afs[FM], wf[FN];
      #pragma unroll
      for (int t = 0; t < FM; ++t) {
        af[t] = *(const bf16x8*)&As[s * 4096 + aoff[t]];
        afs[t] = pairswap(af[t]);
      }
      #pragma unroll
      for (int t = 0; t < FN; ++t)
        wf[t] = *(const bf16x8*)&Bs[s * (BUNITS * 8) + boff[t]];
      #pragma unroll
      for (int tm = 0; tm < FM; ++tm)
        #pragma unroll
        for (int tn = 0; tn < FN; ++tn) {
          acc[tm][tn] = __builtin_amdgcn_mfma_f32_16x16x32_bf16(
              af[tm], wf[tn], acc[tm][tn], 0, 0, 0);
          acc[tm][tn] = __builtin_amdgcn_mfma_f32_16x16x32_bf16(
              afs[tm], wf[tn], acc[tm][tn], 0, 0, 0);
        }
    }
  }

  #pragma unroll
  for (int tm = 0; tm < FM; ++tm) {
    #pragma unroll
    for (int r = 0; r < 4; ++r) {
      int row = row0 + wm + tm * 16 + quad * 4 + r;
      float* cp = C + (size_t)row * ldc + col0 + wn + l16;
      #pragma unroll
      for (int tn = 0; tn < FN; ++tn) cp[tn * 16] = acc[tm][tn][r];
    }
  }
}

// ---------------------------------------------------------------------------
// Generic fp32 GEMM (only the first projection, K=64)
// ---------------------------------------------------------------------------
#define BM 128
#define BN 128
#define BK 16

__global__ __launch_bounds__(256) void gemm_kernel(
    const float* __restrict__ A, int lda, const float* __restrict__ Bw,
    float* __restrict__ C, int ldc, int Nx, int K,
    const float* __restrict__ bias, int act) {
  __shared__ float As[BK][BM];
  __shared__ float Bs[BK][BN];
  int tid = threadIdx.x;
  int tx = tid & 15, ty = tid >> 4;
  int row0 = blockIdx.y * BM;
  int col0 = blockIdx.x * BN;

  float acc[8][8];
  #pragma unroll
  for (int i = 0; i < 8; ++i)
    #pragma unroll
    for (int j = 0; j < 8; ++j) acc[i][j] = 0.f;

  int lr = tid >> 1;
  int lk = (tid & 1) * 8;

  for (int k0 = 0; k0 < K; k0 += BK) {
    const float* ap = A + (size_t)(row0 + lr) * lda + (k0 + lk);
    float4 a0 = *(const float4*)ap;
    float4 a1 = *(const float4*)(ap + 4);
    int bn = col0 + lr;
    float4 b0 = make_float4(0.f, 0.f, 0.f, 0.f);
    float4 b1 = make_float4(0.f, 0.f, 0.f, 0.f);
    if (bn < Nx) {
      const float* bp = Bw + (size_t)bn * K + (k0 + lk);
      b0 = *(const float4*)bp;
      b1 = *(const float4*)(bp + 4);
    }
    __syncthreads();
    As[lk + 0][lr] = a0.x; As[lk + 1][lr] = a0.y;
    As[lk + 2][lr] = a0.z; As[lk + 3][lr] = a0.w;
    As[lk + 4][lr] = a1.x; As[lk + 5][lr] = a1.y;
    As[lk + 6][lr] = a1.z; As[lk + 7][lr] = a1.w;
    Bs[lk + 0][lr] = b0.x; Bs[lk + 1][lr] = b0.y;
    Bs[lk + 2][lr] = b0.z; Bs[lk + 3][lr] = b0.w;
    Bs[lk + 4][lr] = b1.x; Bs[lk + 5][lr] = b1.y;
    Bs[lk + 6][lr] = b1.z; Bs[lk + 7][lr] = b1.w;
    __syncthreads();
    #pragma unroll
    for (int kk = 0; kk < BK; ++kk) {
      float af[8], bf[8];
      *(float4*)(af)     = *(const float4*)(&As[kk][ty * 8]);
      *(float4*)(af + 4) = *(const float4*)(&As[kk][ty * 8 + 4]);
      *(float4*)(bf)     = *(const float4*)(&Bs[kk][tx * 8]);
      *(float4*)(bf + 4) = *(const float4*)(&Bs[kk][tx * 8 + 4]);
      #pragma unroll
      for (int i = 0; i < 8; ++i)
        #pragma unroll
        for (int j = 0; j < 8; ++j)
          acc[i][j] = fmaf(af[i], bf[j], acc[i][j]);
    }
  }
  __syncthreads();

  #pragma unroll
  for (int i = 0; i < 8; ++i) {
    int r = row0 + ty * 8 + i;
    float* cp = C + (size_t)r * ldc + col0 + tx * 8;
    #pragma unroll
    for (int j = 0; j < 8; ++j) {
      int c = col0 + tx * 8 + j;
      if (c < Nx) {
        float v = acc[i][j];
        if (bias) v += bias[c];
        if (act == 1) v = fmaxf(v, 0.f) + log1pf(expf(-fabsf(v)));
        cp[j] = v;
      }
    }
  }
}

// ---------------------------------------------------------------------------
// x_proj specialized: dbl(M,64) = u(M,1024) @ w_x(64,1024)^T
// ---------------------------------------------------------------------------
#define XBK 32
__global__ __launch_bounds__(256) void xproj_kernel(
    const float* __restrict__ u, const float* __restrict__ wx,
    float* __restrict__ dbl) {
  __shared__ float As[XBK][33];
  __shared__ float Bs[XBK][65];
  int tid = threadIdx.x;
  int m0 = blockIdx.x * 32;
  int ty = tid >> 4;
  int tx = tid & 15;
  float acc[2][4];
  #pragma unroll
  for (int i = 0; i < 2; ++i)
    #pragma unroll
    for (int j = 0; j < 4; ++j) acc[i][j] = 0.f;

  for (int k0 = 0; k0 < DIN; k0 += XBK) {
    __syncthreads();
    {
      int row = tid >> 3;
      int kk = (tid & 7) << 2;
      float4 v = *(const float4*)&u[(size_t)(m0 + row) * DIN + k0 + kk];
      As[kk + 0][row] = v.x; As[kk + 1][row] = v.y;
      As[kk + 2][row] = v.z; As[kk + 3][row] = v.w;
    }
    #pragma unroll
    for (int rep = 0; rep < 2; ++rep) {
      int f = tid * 2 + rep;
      int j = f >> 3;
      int kk = (f & 7) << 2;
      float4 v = *(const float4*)&wx[(size_t)j * DIN + k0 + kk];
      Bs[kk + 0][j] = v.x; Bs[kk + 1][j] = v.y;
      Bs[kk + 2][j] = v.z; Bs[kk + 3][j] = v.w;
    }
    __syncthreads();
    #pragma unroll 8
    for (int kk = 0; kk < XBK; ++kk) {
      float af0 = As[kk][ty * 2], af1 = As[kk][ty * 2 + 1];
      float bf[4];
      *(float4*)bf = *(const float4*)&Bs[kk][tx * 4];
      #pragma unroll
      for (int j = 0; j < 4; ++j) {
        acc[0][j] = fmaf(af0, bf[j], acc[0][j]);
        acc[1][j] = fmaf(af1, bf[j], acc[1][j]);
      }
    }
  }
  #pragma unroll
  for (int i = 0; i < 2; ++i) {
    float4 v = make_float4(acc[i][0], acc[i][1], acc[i][2], acc[i][3]);
    *(float4*)&dbl[(size_t)(m0 + ty * 2 + i) * 64 + tx * 4] = v;
  }
}

// ---------------------------------------------------------------------------
// dt_proj specialized: delta = softplus(dbl[:,0:32] @ w_dt^T + b_dt) -> xz
// ---------------------------------------------------------------------------
__global__ __launch_bounds__(256) void dtproj_kernel(
    const float* __restrict__ dbl, const float* __restrict__ wdt,
    const float* __restrict__ bdt, float* __restrict__ xz) {
  __shared__ float dsh[8][DTR];
  int tid = threadIdx.x;
  int d = blockIdx.x * 256 + tid;
  int m0 = blockIdx.y * 8;
  {
    int r = tid >> 5, k = tid & 31;
    dsh[r][k] = dbl[(size_t)(m0 + r) * 64 + k];
  }
  float w[DTR];
  #pragma unroll
  for (int q = 0; q < DTR / 4; ++q)
    *(float4*)&w[q * 4] = *(const float4*)&wdt[(size_t)d * DTR + q * 4];
  float bb = bdt[d];
  __syncthreads();
  #pragma unroll
  for (int r = 0; r < 8; ++r) {
    float s = bb;
    #pragma unroll
    for (int k = 0; k < DTR; ++k) s = fmaf(dsh[r][k], w[k], s);
    float v = fmaxf(s, 0.f) + log1pf(expf(-fabsf(s)));  // softplus
    xz[(size_t)(m0 + r) * 2048 + d] = v;
  }
}

// ---------------------------------------------------------------------------
// causal depthwise conv (k=4) + bias + SiLU, float4 over d. 1 block per row.
// ---------------------------------------------------------------------------
__global__ __launch_bounds__(256) void conv_kernel(
    const float* __restrict__ xz, const float* __restrict__ cw,
    const float* __restrict__ cb, float* __restrict__ u) {
  int m = blockIdx.x;
  int d = threadIdx.x * 4;
  int t = m & (Ldim - 1);
  float4 k0 = *(const float4*)&cw[(d + 0) * 4];
  float4 k1 = *(const float4*)&cw[(d + 1) * 4];
  float4 k2 = *(const float4*)&cw[(d + 2) * 4];
  float4 k3 = *(const float4*)&cw[(d + 3) * 4];
  float4 bias = *(const float4*)&cb[d];
  float4 x0 = *(const float4*)&xz[(size_t)m * 2048 + d];
  float4 a;
  a.x = fmaf(x0.x, k0.w, bias.x);
  a.y = fmaf(x0.y, k1.w, bias.y);
  a.z = fmaf(x0.z, k2.w, bias.z);
  a.w = fmaf(x0.w, k3.w, bias.w);
  if (t >= 1) {
    float4 x1 = *(const float4*)&xz[(size_t)(m - 1) * 2048 + d];
    a.x = fmaf(x1.x, k0.z, a.x); a.y = fmaf(x1.y, k1.z, a.y);
    a.z = fmaf(x1.z, k2.z, a.z); a.w = fmaf(x1.w, k3.z, a.w);
  }
  if (t >= 2) {
    float4 x2 = *(const float4*)&xz[(size_t)(m - 2) * 2048 + d];
    a.x = fmaf(x2.x, k0.y, a.x); a.y = fmaf(x2.y, k1.y, a.y);
    a.z = fmaf(x2.z, k2.y, a.z); a.w = fmaf(x2.w, k3.y, a.w);
  }
  if (t >= 3) {
    float4 x3 = *(const float4*)&xz[(size_t)(m - 3) * 2048 + d];
    a.x = fmaf(x3.x, k0.x, a.x); a.y = fmaf(x3.y, k1.x, a.y);
    a.z = fmaf(x3.z, k2.x, a.z); a.w = fmaf(x3.w, k3.x, a.w);
  }
  float4 o;
  o.x = a.x / (1.f + __expf(-a.x));
  o.y = a.y / (1.f + __expf(-a.y));
  o.z = a.z / (1.f + __expf(-a.z));
  o.w = a.w / (1.f + __expf(-a.w));
  *(float4*)&u[(size_t)m * DIN + d] = o;
}

// ---------------------------------------------------------------------------
// Chunked selective scan pass 1
// ---------------------------------------------------------------------------
__global__ __launch_bounds__(256) void scan1_kernel(
    const float* __restrict__ xz, const float* __restrict__ u,
    const float* __restrict__ dbl, const float* __restrict__ A_log,
    float* __restrict__ Hsum, float* __restrict__ Aprod) {
  __shared__ float Bsh[CHUNK][NST];
  int tid = threadIdx.x;
  int d = blockIdx.x * 256 + tid;
  int c = blockIdx.y;
  int b = blockIdx.z;
  size_t mbase = (size_t)b * Ldim + (size_t)c * CHUNK;
  for (int i = tid; i < CHUNK * NST; i += 256) {
    int t = i >> 4, n = i & 15;
    Bsh[t][n] = dbl[(mbase + t) * 64 + 32 + n];
  }
  float Adn[NST];
  #pragma unroll
  for (int n = 0; n < NST; ++n) Adn[n] = -__expf(A_log[d * NST + n]);
  float h[NST], ap[NST];
  #pragma unroll
  for (int n = 0; n < NST; ++n) { h[n] = 0.f; ap[n] = 1.f; }
  __syncthreads();
  for (int t = 0; t < CHUNK; ++t) {
    size_t m = mbase + t;
    float delta = xz[m * 2048 + d];
    float uv = u[m * DIN + d];
    float du = delta * uv;
    #pragma unroll
    for (int n = 0; n < NST; ++n) {
      float a = __expf(delta * Adn[n]);
      h[n] = fmaf(a, h[n], du * Bsh[t][n]);
      ap[n] *= a;
    }
  }
  size_t base = ((size_t)(b * NCHUNK + c) * NST) * DIN + d;
  #pragma unroll
  for (int n = 0; n < NST; ++n) {
    Hsum[base + (size_t)n * DIN] = h[n];
    Aprod[base + (size_t)n * DIN] = ap[n];
  }
}

// ---------------------------------------------------------------------------
// pass 2: serial carry over the 16 chunks -> exclusive chunk-start state
// ---------------------------------------------------------------------------
__global__ __launch_bounds__(256) void scan2_kernel(
    float* __restrict__ Hsum, const float* __restrict__ Aprod) {
  int idx = blockIdx.x * 256 + threadIdx.x;
  int d = idx & (DIN - 1);
  int bn = idx >> 10;
  int n = bn & 15;
  int b = bn >> 4;
  float carry = 0.f;
  for (int c = 0; c < NCHUNK; ++c) {
    size_t off = ((size_t)((b * NCHUNK + c) * NST + n)) * DIN + d;
    float hs = Hsum[off];
    float apv = Aprod[off];
    Hsum[off] = carry;
    carry = fmaf(apv, carry, hs);
  }
}

// ---------------------------------------------------------------------------
// pass 3: replay with carry, y = C·h + u*Dp, gate silu(z);
// writes y as packed bf16-pair IN PLACE over u.
// ---------------------------------------------------------------------------
__global__ __launch_bounds__(256) void scan3_kernel(
    const float* __restrict__ xz, float* __restrict__ u,
    const float* __restrict__ dbl, const float* __restrict__ A_log,
    const float* __restrict__ Dp, const float* __restrict__ Hstart) {
  __shared__ float Bsh[CHUNK][NST];
  __shared__ float Csh[CHUNK][NST];
  int tid = threadIdx.x;
  int d = blockIdx.x * 256 + tid;
  int c = blockIdx.y;
  int b = blockIdx.z;
  u32* up = (u32*)u;
  size_t mbase = (size_t)b * Ldim + (size_t)c * CHUNK;
  for (int i = tid; i < CHUNK * NST; i += 256) {
    int t = i >> 4, n = i & 15;
    Bsh[t][n] = dbl[(mbase + t) * 64 + 32 + n];
    Csh[t][n] = dbl[(mbase + t) * 64 + 48 + n];
  }
  float Adn[NST];
  #pragma unroll
  for (int n = 0; n < NST; ++n) Adn[n] = -__expf(A_log[d * NST + n]);
  float h[NST];
  size_t base = ((size_t)(b * NCHUNK + c) * NST) * DIN + d;
  #pragma unroll
  for (int n = 0; n < NST; ++n) h[n] = Hstart[base + (size_t)n * DIN];
  float Dpd = Dp[d];
  __syncthreads();
  for (int t = 0; t < CHUNK; ++t) {
    size_t m = mbase + t;
    float delta = xz[m * 2048 + d];
    float uv = u[m * DIN + d];
    float du = delta * uv;
    float y = 0.f;
    #pragma unroll
    for (int n = 0; n < NST; ++n) {
      float a = __expf(delta * Adn[n]);
      h[n] = fmaf(a, h[n], du * Bsh[t][n]);
      y = fmaf(h[n], Csh[t][n], y);
    }
    float z = xz[m * 2048 + DIN + d];
    float sz = z / (1.f + __expf(-z));
    up[m * DIN + d] = packpair((y + uv * Dpd) * sz);
  }
}

// ---------------------------------------------------------------------------
// maxpool over time + fc
// ---------------------------------------------------------------------------
__global__ __launch_bounds__(256) void pool1_kernel(
    const float* __restrict__ h, float* __restrict__ pm) {
  int b = blockIdx.x, r = blockIdx.y;
  int tid = threadIdx.x;
  #pragma unroll
  for (int rep = 0; rep < 2; ++rep) {
    int j = tid + rep * 256;
    float mx = -1e30f;
    size_t base = ((size_t)b * Ldim + r * 128) * Hdim + j;
    for (int t = 0; t < 128; ++t) mx = fmaxf(mx, h[base + (size_t)t * Hdim]);
    pm[((size_t)b * 8 + r) * Hdim + j] = mx;
  }
}

__global__ __launch_bounds__(256) void pool2_kernel(
    const float* __restrict__ pm, const float* __restrict__ fcw,
    const float* __restrict__ fcb, float* __restrict__ out) {
  int b = blockIdx.x, tid = threadIdx.x;
  float acc = 0.f;
  #pragma unroll
  for (int rep = 0; rep < 2; ++rep) {
    int j = tid + rep * 256;
    float mx = -1e30f;
    for (int r = 0; r < 8; ++r) mx = fmaxf(mx, pm[((size_t)b * 8 + r) * Hdim + j]);
    acc += mx * fcw[j];
  }
  __shared__ float red[256];
  red[tid] = acc;
  __syncthreads();
  for (int s = 128; s > 0; s >>= 1) {
    if (tid < s) red[tid] += red[tid + s];
    __syncthreads();
  }
  if (tid == 0) out[b] = red[0] + fcb[0];
}

// ---------------------------------------------------------------------------
extern "C" void kernel_launch(void* const* d_in, const int* in_sizes, int n_in,
                              void* d_out, int out_size, void* d_ws,
                              size_t ws_size, hipStream_t stream) {
  const float* x         = (const float*)d_in[0];
  const float* ln_g      = (const float*)d_in[1];
  const float* ln_b      = (const float*)d_in[2];
  const float* proj_w    = (const float*)d_in[3];
  const float* proj_b    = (const float*)d_in[4];
  const float* in_proj_w = (const float*)d_in[5];
  const float* conv_w    = (const float*)d_in[6];
  const float* conv_b    = (const float*)d_in[7];
  const float* xproj_w   = (const float*)d_in[8];
  const float* dtproj_w  = (const float*)d_in[9];
  const float* dtproj_b  = (const float*)d_in[10];
  const float* A_log     = (const float*)d_in[11];
  const float* Dp        = (const float*)d_in[12];
  const float* out_pw    = (const float*)d_in[13];
  const float* fc_w      = (const float*)d_in[14];
  const float* fc_b      = (const float*)d_in[15];
  float* out = (float*)d_out;

  float* ws   = (float*)d_ws;
  float* xl   = ws;                                 // M*64
  float* hbuf = xl + (size_t)Mrows * Pdim;          // M*512
  float* xz   = hbuf + (size_t)Mrows * Hdim;        // M*2048
  float* ubuf = xz + (size_t)Mrows * 2 * DIN;       // M*1024
  float* dbl  = ubuf + (size_t)Mrows * DIN;         // M*64
  float* pm   = dbl + (size_t)Mrows * 64;           // 8*8*512
  float* Hsum  = hbuf;
  float* Aprod = hbuf + (size_t)Bdim * NCHUNK * NST * DIN;
  u32* hpair   = (u32*)ubuf;
  u32* wpairin = hpair + (size_t)Mrows * Hdim;
  u32* ypair   = (u32*)ubuf;
  u32* wpairo  = (u32*)xz;

  ln_kernel<<<Mrows / 4, 256, 0, stream>>>(x, ln_g, ln_b, xl);
  gemm_kernel<<<dim3(Hdim / BN, Mrows / BM), 256, 0, stream>>>(
      xl, Pdim, proj_w, hbuf, Hdim, Hdim, Pdim, proj_b, 0);

  for (int l = 0; l < NLdim; ++l) {
    const float* w_in = in_proj_w + (size_t)l * 2 * DIN * Hdim;
    const float* cw   = conv_w + (size_t)l * DIN * 4;
    const float* cb   = conv_b + (size_t)l * DIN;
    const float* w_x  = xproj_w + (size_t)l * 64 * DIN;
    const float* w_dt = dtproj_w + (size_t)l * DIN * DTR;
    const float* b_dt = dtproj_b + (size_t)l * DIN;
    const float* Al   = A_log + (size_t)l * DIN * NST;
    const float* Dl   = Dp + (size_t)l * DIN;
    const float* w_o  = out_pw + (size_t)l * Hdim * DIN;

    // pair-split h and w_in in one dispatch, then in_proj pair-GEMM
    pair_split2_kernel<<<Mrows * Hdim / 1024 + 2 * DIN * Hdim / 1024, 256, 0,
                         stream>>>(hbuf, hpair, Mrows * Hdim / 1024, w_in,
                                   wpairin);
    gemm_pair<128><<<dim3(2 * DIN / 128, Mrows / 128), 256, 0, stream>>>(
        (const short*)hpair, (const short*)wpairin, xz, 2 * Hdim, 2 * DIN);
    // u = silu(causal_conv(xc) + cb)
    conv_kernel<<<Mrows, 256, 0, stream>>>(xz, cw, cb, ubuf);
    // dbl = u @ w_x^T   (M,64)
    xproj_kernel<<<Mrows / 32, 256, 0, stream>>>(ubuf, w_x, dbl);
    // delta = softplus(dt @ w_dt^T + b_dt) -> xz[:, 0:1024]
    dtproj_kernel<<<dim3(DIN / 256, Mrows / 8), 256, 0, stream>>>(
        dbl, w_dt, b_dt, xz);
    // chunked selective scan; scan3 emits y as bf16-pairs in place
    scan1_kernel<<<dim3(DIN / 256, NCHUNK, Bdim), 256, 0, stream>>>(
        xz, ubuf, dbl, Al, Hsum, Aprod);
    scan2_kernel<<<Bdim * NST * DIN / 256, 256, 0, stream>>>(Hsum, Aprod);
    scan3_kernel<<<dim3(DIN / 256, NCHUNK, Bdim), 256, 0, stream>>>(
        xz, ubuf, dbl, Al, Dl, Hsum);
    // pair-split w_o (xz dead now), then out_proj pair-GEMM
    pair_split_kernel<<<Hdim * DIN / 1024, 256, 0, stream>>>(w_o, wpairo);
    gemm_pair<64><<<dim3(Hdim / 64, Mrows / 128), 256, 0, stream>>>(
        (const short*)ypair, (const short*)wpairo, hbuf, 2 * DIN, Hdim);
  }

  pool1_kernel<<<dim3(Bdim, 8), 256, 0, stream>>>(hbuf, pm);
  pool2_kernel<<<Bdim, 256, 0, stream>>>(pm, fc_w, fc_b, out);
}

// Round 8
// 1355.726 us; speedup vs baseline: 1.1208x; 1.1208x over previous
//
#include <hip/hip_runtime.h>
#include <math.h>

#define Bdim 8
#define Ldim 1024
#define Pdim 64
#define Hdim 512
#define NLdim 4
#define DIN 1024
#define NST 16
#define DTR 32
#define Mrows (Bdim * Ldim)   // 8192
#define CHUNK 64
#define NCHUNK (Ldim / CHUNK) // 16

typedef unsigned int u32;
typedef __attribute__((ext_vector_type(8))) short bf16x8;
typedef __attribute__((ext_vector_type(4))) float f32x4;

__device__ __forceinline__ short f2bf(float f) {
  union { float f; u32 u; } v; v.f = f;
  u32 r = v.u + 0x7fffu + ((v.u >> 16) & 1u);
  return (short)(r >> 16);
}
__device__ __forceinline__ float bf2f(short h) {
  union { u32 u; float f; } v; v.u = ((u32)(unsigned short)h) << 16;
  return v.f;
}
// fp32 -> packed [hi|lo] bf16 pair (hi = element 2k in memory)
__device__ __forceinline__ u32 packpair(float x) {
  short hi = f2bf(x);
  short lo = f2bf(x - bf2f(hi));
  return (u32)(unsigned short)hi | ((u32)(unsigned short)lo << 16);
}
__device__ __forceinline__ bf16x8 pairswap(bf16x8 v) {
  union { bf16x8 v; u32 u[4]; } a, b;
  a.v = v;
  #pragma unroll
  for (int i = 0; i < 4; ++i) b.u[i] = (a.u[i] << 16) | (a.u[i] >> 16);
  return b.v;
}
__device__ __forceinline__ void gld16(const short* g, short* l) {
  __builtin_amdgcn_global_load_lds(
      (const __attribute__((address_space(1))) void*)g,
      (__attribute__((address_space(3))) void*)l, 16, 0, 0);
}
__device__ __forceinline__ int swz(int r) { return (r & 3) ^ ((r >> 2) & 3); }

// ---------------------------------------------------------------------------
// minmax-normalize + LayerNorm, one wave per row of 64 elements
// ---------------------------------------------------------------------------
__global__ __launch_bounds__(256) void ln_kernel(
    const float* __restrict__ x, const float* __restrict__ g,
    const float* __restrict__ bta, float* __restrict__ xl) {
  int row = blockIdx.x * 4 + (threadIdx.x >> 6);
  int lane = threadIdx.x & 63;
  float v = x[(size_t)row * Pdim + lane];
  float mn = v, mx = v;
  #pragma unroll
  for (int m = 1; m < 64; m <<= 1) {
    mn = fminf(mn, __shfl_xor(mn, m, 64));
    mx = fmaxf(mx, __shfl_xor(mx, m, 64));
  }
  float xn = (v - mn) / (mx - mn + 1e-6f);
  float s = xn, s2 = xn * xn;
  #pragma unroll
  for (int m = 1; m < 64; m <<= 1) {
    s += __shfl_xor(s, m, 64);
    s2 += __shfl_xor(s2, m, 64);
  }
  float mu = s * (1.f / 64.f);
  float var = s2 * (1.f / 64.f) - mu * mu;
  float out = (xn - mu) * rsqrtf(var + 1e-5f) * g[lane] + bta[lane];
  xl[(size_t)row * Pdim + lane] = out;
}

// ---------------------------------------------------------------------------
// elementwise fp32 -> packed bf16-pair. single buffer version
// ---------------------------------------------------------------------------
__global__ __launch_bounds__(256) void pair_split_kernel(
    const float* __restrict__ X, u32* __restrict__ Xp) {
  int i = (blockIdx.x * 256 + threadIdx.x) * 4;
  float4 v = *(const float4*)&X[i];
  uint4 o;
  o.x = packpair(v.x); o.y = packpair(v.y);
  o.z = packpair(v.z); o.w = packpair(v.w);
  *(uint4*)&Xp[i] = o;
}

// two-buffer version (h + w_in in one dispatch)
__global__ __launch_bounds__(256) void pair_split2_kernel(
    const float* __restrict__ X0, u32* __restrict__ P0, int nblk0,
    const float* __restrict__ X1, u32* __restrict__ P1) {
  int blk = blockIdx.x;
  const float* X;
  u32* P;
  int i;
  if (blk < nblk0) {
    X = X0; P = P0; i = (blk * 256 + threadIdx.x) * 4;
  } else {
    X = X1; P = P1; i = ((blk - nblk0) * 256 + threadIdx.x) * 4;
  }
  float4 v = *(const float4*)&X[i];
  uint4 o;
  o.x = packpair(v.x); o.y = packpair(v.y);
  o.z = packpair(v.z); o.w = packpair(v.w);
  *(uint4*)&P[i] = o;
}

// ---------------------------------------------------------------------------
// bf16-pair MFMA GEMM: C(M,Nx) = A(M,K as pairs) * W(Nx,K)^T, fp32 out.
// XOR-swizzled LDS, BK=64 shorts (2 subtiles per barrier pair).
// Tile 128 x TN (128 or 64), 256 threads.
// Note: SQ_LDS_BANK_CONFLICT ~2/read here is the benign wave64 2-way
// aliasing (free per m136) — do not chase it.
// ---------------------------------------------------------------------------
template <int TN>
__global__ __launch_bounds__(256) void gemm_pair(
    const short* __restrict__ Ab, const short* __restrict__ Wb,
    float* __restrict__ C, int Kp, int ldc) {
  constexpr int FM = (TN == 128) ? 4 : 2;
  constexpr int FN = 4;
  constexpr int BUNITS = TN * 4;            // units per B subtile
  __shared__ short As[2 * 128 * 32];        // 2 subtiles of 512 units
  __shared__ short Bs[2 * TN * 32];
  int tid = threadIdx.x;
  int lane = tid & 63;
  int wave = tid >> 6;
  int quad = lane >> 4, l16 = lane & 15;
  int wm = (TN == 128) ? (wave & 1) * 64 : wave * 32;
  int wn = (TN == 128) ? (wave >> 1) * 64 : 0;
  int row0 = blockIdx.y * 128, col0 = blockIdx.x * TN;

  f32x4 acc[FM][FN];
  #pragma unroll
  for (int i = 0; i < FM; ++i)
    #pragma unroll
    for (int j = 0; j < FN; ++j) acc[i][j] = (f32x4){0.f, 0.f, 0.f, 0.f};

  int uA0 = tid, uA1 = tid + 256;
  const short* gA0 =
      Ab + (size_t)(row0 + (uA0 >> 2)) * Kp + (((uA0 & 3) ^ swz(uA0 >> 2)) << 3);
  const short* gA1 =
      Ab + (size_t)(row0 + (uA1 >> 2)) * Kp + (((uA1 & 3) ^ swz(uA1 >> 2)) << 3);
  short* lA0 = &As[uA0 * 8];
  short* lA1 = &As[uA1 * 8];
  const short* gB0 =
      Wb + (size_t)(col0 + (uA0 >> 2)) * Kp + (((uA0 & 3) ^ swz(uA0 >> 2)) << 3);
  short* lB0 = &Bs[uA0 * 8];
  const short* gB1 = nullptr;
  short* lB1 = nullptr;
  if (TN == 128) {
    gB1 = Wb + (size_t)(col0 + (uA1 >> 2)) * Kp +
          (((uA1 & 3) ^ swz(uA1 >> 2)) << 3);
    lB1 = &Bs[uA1 * 8];
  }

  int aoff[FM], boff[FN];
  #pragma unroll
  for (int t = 0; t < FM; ++t) {
    int r = wm + t * 16 + l16;
    aoff[t] = (r * 4 + (quad ^ swz(r))) * 8;
  }
  #pragma unroll
  for (int t = 0; t < FN; ++t) {
    int r = wn + t * 16 + l16;
    boff[t] = (r * 4 + (quad ^ swz(r))) * 8;
  }

  for (int k0 = 0; k0 < Kp; k0 += 64) {
    __syncthreads();
    gld16(gA0 + k0, lA0);
    gld16(gA0 + k0 + 32, lA0 + 4096);
    gld16(gA1 + k0, lA1);
    gld16(gA1 + k0 + 32, lA1 + 4096);
    gld16(gB0 + k0, lB0);
    gld16(gB0 + k0 + 32, lB0 + BUNITS * 8);
    if (TN == 128) {
      gld16(gB1 + k0, lB1);
      gld16(gB1 + k0 + 32, lB1 + BUNITS * 8);
    }
    __syncthreads();
    #pragma unroll
    for (int s = 0; s < 2; ++s) {
      bf16x8 af[FM], afs[FM], wf[FN];
      #pragma unroll
      for (int t = 0; t < FM; ++t) {
        af[t] = *(const bf16x8*)&As[s * 4096 + aoff[t]];
        afs[t] = pairswap(af[t]);
      }
      #pragma unroll
      for (int t = 0; t < FN; ++t)
        wf[t] = *(const bf16x8*)&Bs[s * (BUNITS * 8) + boff[t]];
      #pragma unroll
      for (int tm = 0; tm < FM; ++tm)
        #pragma unroll
        for (int tn = 0; tn < FN; ++tn) {
          acc[tm][tn] = __builtin_amdgcn_mfma_f32_16x16x32_bf16(
              af[tm], wf[tn], acc[tm][tn], 0, 0, 0);
          acc[tm][tn] = __builtin_amdgcn_mfma_f32_16x16x32_bf16(
              afs[tm], wf[tn], acc[tm][tn], 0, 0, 0);
        }
    }
  }

  #pragma unroll
  for (int tm = 0; tm < FM; ++tm) {
    #pragma unroll
    for (int r = 0; r < 4; ++r) {
      int row = row0 + wm + tm * 16 + quad * 4 + r;
      float* cp = C + (size_t)row * ldc + col0 + wn + l16;
      #pragma unroll
      for (int tn = 0; tn < FN; ++tn) cp[tn * 16] = acc[tm][tn][r];
    }
  }
}

// ---------------------------------------------------------------------------
// Generic fp32 GEMM (only the first projection, K=64)
// ---------------------------------------------------------------------------
#define BM 128
#define BN 128
#define BK 16

__global__ __launch_bounds__(256) void gemm_kernel(
    const float* __restrict__ A, int lda, const float* __restrict__ Bw,
    float* __restrict__ C, int ldc, int Nx, int K,
    const float* __restrict__ bias, int act) {
  __shared__ float As[BK][BM];
  __shared__ float Bs[BK][BN];
  int tid = threadIdx.x;
  int tx = tid & 15, ty = tid >> 4;
  int row0 = blockIdx.y * BM;
  int col0 = blockIdx.x * BN;

  float acc[8][8];
  #pragma unroll
  for (int i = 0; i < 8; ++i)
    #pragma unroll
    for (int j = 0; j < 8; ++j) acc[i][j] = 0.f;

  int lr = tid >> 1;
  int lk = (tid & 1) * 8;

  for (int k0 = 0; k0 < K; k0 += BK) {
    const float* ap = A + (size_t)(row0 + lr) * lda + (k0 + lk);
    float4 a0 = *(const float4*)ap;
    float4 a1 = *(const float4*)(ap + 4);
    int bn = col0 + lr;
    float4 b0 = make_float4(0.f, 0.f, 0.f, 0.f);
    float4 b1 = make_float4(0.f, 0.f, 0.f, 0.f);
    if (bn < Nx) {
      const float* bp = Bw + (size_t)bn * K + (k0 + lk);
      b0 = *(const float4*)bp;
      b1 = *(const float4*)(bp + 4);
    }
    __syncthreads();
    As[lk + 0][lr] = a0.x; As[lk + 1][lr] = a0.y;
    As[lk + 2][lr] = a0.z; As[lk + 3][lr] = a0.w;
    As[lk + 4][lr] = a1.x; As[lk + 5][lr] = a1.y;
    As[lk + 6][lr] = a1.z; As[lk + 7][lr] = a1.w;
    Bs[lk + 0][lr] = b0.x; Bs[lk + 1][lr] = b0.y;
    Bs[lk + 2][lr] = b0.z; Bs[lk + 3][lr] = b0.w;
    Bs[lk + 4][lr] = b1.x; Bs[lk + 5][lr] = b1.y;
    Bs[lk + 6][lr] = b1.z; Bs[lk + 7][lr] = b1.w;
    __syncthreads();
    #pragma unroll
    for (int kk = 0; kk < BK; ++kk) {
      float af[8], bf[8];
      *(float4*)(af)     = *(const float4*)(&As[kk][ty * 8]);
      *(float4*)(af + 4) = *(const float4*)(&As[kk][ty * 8 + 4]);
      *(float4*)(bf)     = *(const float4*)(&Bs[kk][tx * 8]);
      *(float4*)(bf + 4) = *(const float4*)(&Bs[kk][tx * 8 + 4]);
      #pragma unroll
      for (int i = 0; i < 8; ++i)
        #pragma unroll
        for (int j = 0; j < 8; ++j)
          acc[i][j] = fmaf(af[i], bf[j], acc[i][j]);
    }
  }
  __syncthreads();

  #pragma unroll
  for (int i = 0; i < 8; ++i) {
    int r = row0 + ty * 8 + i;
    float* cp = C + (size_t)r * ldc + col0 + tx * 8;
    #pragma unroll
    for (int j = 0; j < 8; ++j) {
      int c = col0 + tx * 8 + j;
      if (c < Nx) {
        float v = acc[i][j];
        if (bias) v += bias[c];
        if (act == 1) v = fmaxf(v, 0.f) + log1pf(expf(-fabsf(v)));
        cp[j] = v;
      }
    }
  }
}

// ---------------------------------------------------------------------------
// x_proj stage 1 (K-split): part[kc][M][64] = u[:, kc*256:+256] @ wx^T chunk
// 64 rows x 64 cols per block, grid = (M/64, 4) = 512 blocks (2/CU).
// 4x4 microtile, float4 LDS reads (broadcast / 2-way only).
// ---------------------------------------------------------------------------
#define XR 64
#define XKC 256
__global__ __launch_bounds__(256) void xproj1_kernel(
    const float* __restrict__ u, const float* __restrict__ wx,
    float* __restrict__ part) {
  __shared__ float As[32][XR + 1];   // [k][row]
  __shared__ float Bs[32][65];       // [k][col]
  int tid = threadIdx.x;
  int m0 = blockIdx.x * XR;
  int k00 = blockIdx.y * XKC;
  int tr = tid >> 4, tc = tid & 15;
  float acc[4][4];
  #pragma unroll
  for (int i = 0; i < 4; ++i)
    #pragma unroll
    for (int j = 0; j < 4; ++j) acc[i][j] = 0.f;

  for (int k0 = 0; k0 < XKC; k0 += 32) {
    __syncthreads();
    #pragma unroll
    for (int rep = 0; rep < 2; ++rep) {
      int f = tid * 2 + rep;
      int row = f >> 3;              // 0..63 (also used as col for B)
      int kk = (f & 7) << 2;
      float4 v = *(const float4*)&u[(size_t)(m0 + row) * DIN + k00 + k0 + kk];
      As[kk + 0][row] = v.x; As[kk + 1][row] = v.y;
      As[kk + 2][row] = v.z; As[kk + 3][row] = v.w;
      float4 w = *(const float4*)&wx[(size_t)row * DIN + k00 + k0 + kk];
      Bs[kk + 0][row] = w.x; Bs[kk + 1][row] = w.y;
      Bs[kk + 2][row] = w.z; Bs[kk + 3][row] = w.w;
    }
    __syncthreads();
    #pragma unroll
    for (int kk = 0; kk < 32; ++kk) {
      float a[4], b[4];
      *(float4*)a = *(const float4*)&As[kk][tr * 4];
      *(float4*)b = *(const float4*)&Bs[kk][tc * 4];
      #pragma unroll
      for (int i = 0; i < 4; ++i)
        #pragma unroll
        for (int j = 0; j < 4; ++j)
          acc[i][j] = fmaf(a[i], b[j], acc[i][j]);
    }
  }
  size_t base = ((size_t)blockIdx.y * Mrows + m0) * 64;
  #pragma unroll
  for (int i = 0; i < 4; ++i) {
    float4 v = make_float4(acc[i][0], acc[i][1], acc[i][2], acc[i][3]);
    *(float4*)&part[base + (size_t)(tr * 4 + i) * 64 + tc * 4] = v;
  }
}

// stage 2: dbl = sum of 4 K-chunk partials
__global__ __launch_bounds__(256) void xreduce_kernel(
    const float* __restrict__ part, float* __restrict__ dbl) {
  int i = (blockIdx.x * 256 + threadIdx.x) * 4;
  const size_t S = (size_t)Mrows * 64;
  float4 a = *(const float4*)&part[i];
  float4 b = *(const float4*)&part[i + S];
  float4 c = *(const float4*)&part[i + 2 * S];
  float4 d = *(const float4*)&part[i + 3 * S];
  float4 o;
  o.x = (a.x + b.x) + (c.x + d.x);
  o.y = (a.y + b.y) + (c.y + d.y);
  o.z = (a.z + b.z) + (c.z + d.z);
  o.w = (a.w + b.w) + (c.w + d.w);
  *(float4*)&dbl[i] = o;
}

// ---------------------------------------------------------------------------
// dt_proj specialized: delta = softplus(dbl[:,0:32] @ w_dt^T + b_dt) -> xz
// ---------------------------------------------------------------------------
__global__ __launch_bounds__(256) void dtproj_kernel(
    const float* __restrict__ dbl, const float* __restrict__ wdt,
    const float* __restrict__ bdt, float* __restrict__ xz) {
  __shared__ float dsh[8][DTR];
  int tid = threadIdx.x;
  int d = blockIdx.x * 256 + tid;
  int m0 = blockIdx.y * 8;
  {
    int r = tid >> 5, k = tid & 31;
    dsh[r][k] = dbl[(size_t)(m0 + r) * 64 + k];
  }
  float w[DTR];
  #pragma unroll
  for (int q = 0; q < DTR / 4; ++q)
    *(float4*)&w[q * 4] = *(const float4*)&wdt[(size_t)d * DTR + q * 4];
  float bb = bdt[d];
  __syncthreads();
  #pragma unroll
  for (int r = 0; r < 8; ++r) {
    float s = bb;
    #pragma unroll
    for (int k = 0; k < DTR; ++k) s = fmaf(dsh[r][k], w[k], s);
    float v = fmaxf(s, 0.f) + log1pf(expf(-fabsf(s)));  // softplus
    xz[(size_t)(m0 + r) * 2048 + d] = v;
  }
}

// ---------------------------------------------------------------------------
// causal depthwise conv (k=4) + bias + SiLU, float4 over d. 1 block per row.
// ---------------------------------------------------------------------------
__global__ __launch_bounds__(256) void conv_kernel(
    const float* __restrict__ xz, const float* __restrict__ cw,
    const float* __restrict__ cb, float* __restrict__ u) {
  int m = blockIdx.x;
  int d = threadIdx.x * 4;
  int t = m & (Ldim - 1);
  float4 k0 = *(const float4*)&cw[(d + 0) * 4];
  float4 k1 = *(const float4*)&cw[(d + 1) * 4];
  float4 k2 = *(const float4*)&cw[(d + 2) * 4];
  float4 k3 = *(const float4*)&cw[(d + 3) * 4];
  float4 bias = *(const float4*)&cb[d];
  float4 x0 = *(const float4*)&xz[(size_t)m * 2048 + d];
  float4 a;
  a.x = fmaf(x0.x, k0.w, bias.x);
  a.y = fmaf(x0.y, k1.w, bias.y);
  a.z = fmaf(x0.z, k2.w, bias.z);
  a.w = fmaf(x0.w, k3.w, bias.w);
  if (t >= 1) {
    float4 x1 = *(const float4*)&xz[(size_t)(m - 1) * 2048 + d];
    a.x = fmaf(x1.x, k0.z, a.x); a.y = fmaf(x1.y, k1.z, a.y);
    a.z = fmaf(x1.z, k2.z, a.z); a.w = fmaf(x1.w, k3.z, a.w);
  }
  if (t >= 2) {
    float4 x2 = *(const float4*)&xz[(size_t)(m - 2) * 2048 + d];
    a.x = fmaf(x2.x, k0.y, a.x); a.y = fmaf(x2.y, k1.y, a.y);
    a.z = fmaf(x2.z, k2.y, a.z); a.w = fmaf(x2.w, k3.y, a.w);
  }
  if (t >= 3) {
    float4 x3 = *(const float4*)&xz[(size_t)(m - 3) * 2048 + d];
    a.x = fmaf(x3.x, k0.x, a.x); a.y = fmaf(x3.y, k1.x, a.y);
    a.z = fmaf(x3.z, k2.x, a.z); a.w = fmaf(x3.w, k3.x, a.w);
  }
  float4 o;
  o.x = a.x / (1.f + __expf(-a.x));
  o.y = a.y / (1.f + __expf(-a.y));
  o.z = a.z / (1.f + __expf(-a.z));
  o.w = a.w / (1.f + __expf(-a.w));
  *(float4*)&u[(size_t)m * DIN + d] = o;
}

// ---------------------------------------------------------------------------
// Chunked selective scan pass 1
// ---------------------------------------------------------------------------
__global__ __launch_bounds__(256) void scan1_kernel(
    const float* __restrict__ xz, const float* __restrict__ u,
    const float* __restrict__ dbl, const float* __restrict__ A_log,
    float* __restrict__ Hsum, float* __restrict__ Aprod) {
  __shared__ float Bsh[CHUNK][NST];
  int tid = threadIdx.x;
  int d = blockIdx.x * 256 + tid;
  int c = blockIdx.y;
  int b = blockIdx.z;
  size_t mbase = (size_t)b * Ldim + (size_t)c * CHUNK;
  for (int i = tid; i < CHUNK * NST; i += 256) {
    int t = i >> 4, n = i & 15;
    Bsh[t][n] = dbl[(mbase + t) * 64 + 32 + n];
  }
  float Adn[NST];
  #pragma unroll
  for (int n = 0; n < NST; ++n) Adn[n] = -__expf(A_log[d * NST + n]);
  float h[NST], ap[NST];
  #pragma unroll
  for (int n = 0; n < NST; ++n) { h[n] = 0.f; ap[n] = 1.f; }
  __syncthreads();
  for (int t = 0; t < CHUNK; ++t) {
    size_t m = mbase + t;
    float delta = xz[m * 2048 + d];
    float uv = u[m * DIN + d];
    float du = delta * uv;
    #pragma unroll
    for (int n = 0; n < NST; ++n) {
      float a = __expf(delta * Adn[n]);
      h[n] = fmaf(a, h[n], du * Bsh[t][n]);
      ap[n] *= a;
    }
  }
  size_t base = ((size_t)(b * NCHUNK + c) * NST) * DIN + d;
  #pragma unroll
  for (int n = 0; n < NST; ++n) {
    Hsum[base + (size_t)n * DIN] = h[n];
    Aprod[base + (size_t)n * DIN] = ap[n];
  }
}

// ---------------------------------------------------------------------------
// pass 2: serial carry over the 16 chunks -> exclusive chunk-start state
// ---------------------------------------------------------------------------
__global__ __launch_bounds__(256) void scan2_kernel(
    float* __restrict__ Hsum, const float* __restrict__ Aprod) {
  int idx = blockIdx.x * 256 + threadIdx.x;
  int d = idx & (DIN - 1);
  int bn = idx >> 10;
  int n = bn & 15;
  int b = bn >> 4;
  float carry = 0.f;
  for (int c = 0; c < NCHUNK; ++c) {
    size_t off = ((size_t)((b * NCHUNK + c) * NST + n)) * DIN + d;
    float hs = Hsum[off];
    float apv = Aprod[off];
    Hsum[off] = carry;
    carry = fmaf(apv, carry, hs);
  }
}

// ---------------------------------------------------------------------------
// pass 3: replay with carry, y = C·h + u*Dp, gate silu(z);
// writes y as packed bf16-pair IN PLACE over u.
// ---------------------------------------------------------------------------
__global__ __launch_bounds__(256) void scan3_kernel(
    const float* __restrict__ xz, float* __restrict__ u,
    const float* __restrict__ dbl, const float* __restrict__ A_log,
    const float* __restrict__ Dp, const float* __restrict__ Hstart) {
  __shared__ float Bsh[CHUNK][NST];
  __shared__ float Csh[CHUNK][NST];
  int tid = threadIdx.x;
  int d = blockIdx.x * 256 + tid;
  int c = blockIdx.y;
  int b = blockIdx.z;
  u32* up = (u32*)u;
  size_t mbase = (size_t)b * Ldim + (size_t)c * CHUNK;
  for (int i = tid; i < CHUNK * NST; i += 256) {
    int t = i >> 4, n = i & 15;
    Bsh[t][n] = dbl[(mbase + t) * 64 + 32 + n];
    Csh[t][n] = dbl[(mbase + t) * 64 + 48 + n];
  }
  float Adn[NST];
  #pragma unroll
  for (int n = 0; n < NST; ++n) Adn[n] = -__expf(A_log[d * NST + n]);
  float h[NST];
  size_t base = ((size_t)(b * NCHUNK + c) * NST) * DIN + d;
  #pragma unroll
  for (int n = 0; n < NST; ++n) h[n] = Hstart[base + (size_t)n * DIN];
  float Dpd = Dp[d];
  __syncthreads();
  for (int t = 0; t < CHUNK; ++t) {
    size_t m = mbase + t;
    float delta = xz[m * 2048 + d];
    float uv = u[m * DIN + d];
    float du = delta * uv;
    float y = 0.f;
    #pragma unroll
    for (int n = 0; n < NST; ++n) {
      float a = __expf(delta * Adn[n]);
      h[n] = fmaf(a, h[n], du * Bsh[t][n]);
      y = fmaf(h[n], Csh[t][n], y);
    }
    float z = xz[m * 2048 + DIN + d];
    float sz = z / (1.f + __expf(-z));
    up[m * DIN + d] = packpair((y + uv * Dpd) * sz);
  }
}

// ---------------------------------------------------------------------------
// maxpool over time + fc
// ---------------------------------------------------------------------------
__global__ __launch_bounds__(256) void pool1_kernel(
    const float* __restrict__ h, float* __restrict__ pm) {
  int b = blockIdx.x, r = blockIdx.y;
  int tid = threadIdx.x;
  #pragma unroll
  for (int rep = 0; rep < 2; ++rep) {
    int j = tid + rep * 256;
    float mx = -1e30f;
    size_t base = ((size_t)b * Ldim + r * 128) * Hdim + j;
    for (int t = 0; t < 128; ++t) mx = fmaxf(mx, h[base + (size_t)t * Hdim]);
    pm[((size_t)b * 8 + r) * Hdim + j] = mx;
  }
}

__global__ __launch_bounds__(256) void pool2_kernel(
    const float* __restrict__ pm, const float* __restrict__ fcw,
    const float* __restrict__ fcb, float* __restrict__ out) {
  int b = blockIdx.x, tid = threadIdx.x;
  float acc = 0.f;
  #pragma unroll
  for (int rep = 0; rep < 2; ++rep) {
    int j = tid + rep * 256;
    float mx = -1e30f;
    for (int r = 0; r < 8; ++r) mx = fmaxf(mx, pm[((size_t)b * 8 + r) * Hdim + j]);
    acc += mx * fcw[j];
  }
  __shared__ float red[256];
  red[tid] = acc;
  __syncthreads();
  for (int s = 128; s > 0; s >>= 1) {
    if (tid < s) red[tid] += red[tid + s];
    __syncthreads();
  }
  if (tid == 0) out[b] = red[0] + fcb[0];
}

// ---------------------------------------------------------------------------
extern "C" void kernel_launch(void* const* d_in, const int* in_sizes, int n_in,
                              void* d_out, int out_size, void* d_ws,
                              size_t ws_size, hipStream_t stream) {
  const float* x         = (const float*)d_in[0];
  const float* ln_g      = (const float*)d_in[1];
  const float* ln_b      = (const float*)d_in[2];
  const float* proj_w    = (const float*)d_in[3];
  const float* proj_b    = (const float*)d_in[4];
  const float* in_proj_w = (const float*)d_in[5];
  const float* conv_w    = (const float*)d_in[6];
  const float* conv_b    = (const float*)d_in[7];
  const float* xproj_w   = (const float*)d_in[8];
  const float* dtproj_w  = (const float*)d_in[9];
  const float* dtproj_b  = (const float*)d_in[10];
  const float* A_log     = (const float*)d_in[11];
  const float* Dp        = (const float*)d_in[12];
  const float* out_pw    = (const float*)d_in[13];
  const float* fc_w      = (const float*)d_in[14];
  const float* fc_b      = (const float*)d_in[15];
  float* out = (float*)d_out;

  float* ws   = (float*)d_ws;
  float* xl   = ws;                                 // M*64
  float* hbuf = xl + (size_t)Mrows * Pdim;          // M*512
  float* xz   = hbuf + (size_t)Mrows * Hdim;        // M*2048
  float* ubuf = xz + (size_t)Mrows * 2 * DIN;       // M*1024
  float* dbl  = ubuf + (size_t)Mrows * DIN;         // M*64
  float* pm   = dbl + (size_t)Mrows * 64;           // 8*8*512
  // scan scratch + xproj partials overlay hbuf (dead between in_proj's
  // pair-split and out_proj's write); xpart dead before Hsum is written.
  float* Hsum  = hbuf;
  float* Aprod = hbuf + (size_t)Bdim * NCHUNK * NST * DIN;
  float* xpart = hbuf;                              // 4*M*64 = 2M floats
  u32* hpair   = (u32*)ubuf;
  u32* wpairin = hpair + (size_t)Mrows * Hdim;
  u32* ypair   = (u32*)ubuf;
  u32* wpairo  = (u32*)xz;

  ln_kernel<<<Mrows / 4, 256, 0, stream>>>(x, ln_g, ln_b, xl);
  gemm_kernel<<<dim3(Hdim / BN, Mrows / BM), 256, 0, stream>>>(
      xl, Pdim, proj_w, hbuf, Hdim, Hdim, Pdim, proj_b, 0);

  for (int l = 0; l < NLdim; ++l) {
    const float* w_in = in_proj_w + (size_t)l * 2 * DIN * Hdim;
    const float* cw   = conv_w + (size_t)l * DIN * 4;
    const float* cb   = conv_b + (size_t)l * DIN;
    const float* w_x  = xproj_w + (size_t)l * 64 * DIN;
    const float* w_dt = dtproj_w + (size_t)l * DIN * DTR;
    const float* b_dt = dtproj_b + (size_t)l * DIN;
    const float* Al   = A_log + (size_t)l * DIN * NST;
    const float* Dl   = Dp + (size_t)l * DIN;
    const float* w_o  = out_pw + (size_t)l * Hdim * DIN;

    // pair-split h and w_in in one dispatch, then in_proj pair-GEMM
    pair_split2_kernel<<<Mrows * Hdim / 1024 + 2 * DIN * Hdim / 1024, 256, 0,
                         stream>>>(hbuf, hpair, Mrows * Hdim / 1024, w_in,
                                   wpairin);
    gemm_pair<128><<<dim3(2 * DIN / 128, Mrows / 128), 256, 0, stream>>>(
        (const short*)hpair, (const short*)wpairin, xz, 2 * Hdim, 2 * DIN);
    // u = silu(causal_conv(xc) + cb)
    conv_kernel<<<Mrows, 256, 0, stream>>>(xz, cw, cb, ubuf);
    // dbl = u @ w_x^T   (M,64) — K-split 2-stage
    xproj1_kernel<<<dim3(Mrows / XR, 4), 256, 0, stream>>>(ubuf, w_x, xpart);
    xreduce_kernel<<<Mrows * 64 / 1024, 256, 0, stream>>>(xpart, dbl);
    // delta = softplus(dt @ w_dt^T + b_dt) -> xz[:, 0:1024]
    dtproj_kernel<<<dim3(DIN / 256, Mrows / 8), 256, 0, stream>>>(
        dbl, w_dt, b_dt, xz);
    // chunked selective scan; scan3 emits y as bf16-pairs in place
    scan1_kernel<<<dim3(DIN / 256, NCHUNK, Bdim), 256, 0, stream>>>(
        xz, ubuf, dbl, Al, Hsum, Aprod);
    scan2_kernel<<<Bdim * NST * DIN / 256, 256, 0, stream>>>(Hsum, Aprod);
    scan3_kernel<<<dim3(DIN / 256, NCHUNK, Bdim), 256, 0, stream>>>(
        xz, ubuf, dbl, Al, Dl, Hsum);
    // pair-split w_o (xz dead now), then out_proj pair-GEMM
    pair_split_kernel<<<Hdim * DIN / 1024, 256, 0, stream>>>(w_o, wpairo);
    gemm_pair<64><<<dim3(Hdim / 64, Mrows / 128), 256, 0, stream>>>(
        (const short*)ypair, (const short*)wpairo, hbuf, 2 * DIN, Hdim);
  }

  pool1_kernel<<<dim3(Bdim, 8), 256, 0, stream>>>(hbuf, pm);
  pool2_kernel<<<Bdim, 256, 0, stream>>>(pm, fc_w, fc_b, out);
}